// Round 6
// baseline (73.248 us; speedup 1.0000x reference)
//
#include <hip/hip_runtime.h>
#include <stdint.h>
#include <stddef.h>

// BlockLinear: out[b, g*512+n] = sum_m x[b, g*512+m] * blocks[g, m, n]
// G=8, M=N=512, TOKENS=8192. fp32 in/out; compute in bf16 MFMA.
// Round 6: R5 + (a) conflict-free swizzle for 64B rows ((row>>1)&3),
// (b) counted-vmcnt pipeline with raw s_barrier (no vmcnt(0) drain of the
// B prefetch). 4-wave blocks, BM=64 BN=256 BK=32, 40KB LDS, 4 blocks/CU.

typedef __attribute__((ext_vector_type(8))) short sv8;   // 8 x bf16 fragment
typedef __attribute__((ext_vector_type(4))) float fv4;   // 4 x f32 accum

__device__ __forceinline__ uint32_t f2bf(float f) {
    union { float f; uint32_t u; } v; v.f = f;
    uint32_t u = v.u;
    u += 0x7FFFu + ((u >> 16) & 1u);   // RNE
    return u >> 16;
}
__device__ __forceinline__ uint32_t pk2(float a, float b) {
    return f2bf(a) | (f2bf(b) << 16);
}
__device__ __forceinline__ void gl_lds16(const void* g, void* lds) {
    __builtin_amdgcn_global_load_lds(
        (const __attribute__((address_space(1))) void*)g,
        (__attribute__((address_space(3))) void*)lds, 16, 0, 0);
}

#define BAR()   __builtin_amdgcn_s_barrier()
#define SB0()   __builtin_amdgcn_sched_barrier(0)
#define LGKM0() do { asm volatile("s_waitcnt lgkmcnt(0)" ::: "memory"); SB0(); } while (0)
#define VM(N)   asm volatile("s_waitcnt vmcnt(" #N ")" ::: "memory")

// bTgl[g][kt][n*4+slot] : 16B unit = bf16(blocks[g][kt*32 + c*8 + e][n]),
// e=0..7, c = slot ^ ((n>>1)&3).  8 g x 16 kt x 2048 units x 16B = 4 MiB.
__global__ void bl_pack(const float* __restrict__ blocks,
                        unsigned short* __restrict__ bTgl) {
    __shared__ float tile[64][65];
    const int g  = blockIdx.z;
    const int mt = blockIdx.y;           // 64 m-rows -> kt = mt*2 + {0,1}
    const int n0 = blockIdx.x * 64;
    const float* src = blocks + (size_t)g * 512 * 512;
    const int lane = threadIdx.x & 63;
    const int r0   = threadIdx.x >> 6;   // 0..3
    for (int r = r0; r < 64; r += 4)
        tile[r][lane] = src[(size_t)(mt * 64 + r) * 512 + n0 + lane];
    __syncthreads();
    const int t    = threadIdx.x;        // 0..255
    const int nl   = t >> 2;
    const int slot = t & 3;
    const int c    = slot ^ ((nl >> 1) & 3);   // n0 multiple of 64
#pragma unroll
    for (int ktl = 0; ktl < 2; ++ktl) {
        const int mb = ktl * 32 + c * 8;
        uint4 w;
        w.x = pk2(tile[mb + 0][nl], tile[mb + 1][nl]);
        w.y = pk2(tile[mb + 2][nl], tile[mb + 3][nl]);
        w.z = pk2(tile[mb + 4][nl], tile[mb + 5][nl]);
        w.w = pk2(tile[mb + 6][nl], tile[mb + 7][nl]);
        const size_t u = ((size_t)(g * 16 + mt * 2 + ktl)) * 2048 + (n0 + nl) * 4 + slot;
        *(uint4*)(bTgl + u * 8) = w;
    }
}

// Main GEMM: BM=64, BN=256, BK=32, 256 threads (4 waves, 1Mx4N),
// wave tile 64x64 = 4x4 fragments of 16x16x32 bf16 MFMA.
// Double-buffered LDS (40 KiB -> 4 blocks/CU); raw-barrier counted-vmcnt
// pipeline: B(t+1) gl_lds stays in flight across both barriers of tile t.
__global__ __launch_bounds__(256, 4) void bl_gemm(
    const float* __restrict__ x,              // [8192][4096]
    const unsigned short* __restrict__ bTgl,  // packed B, see bl_pack
    float* __restrict__ out)                  // [8192][4096]
{
    __shared__ __align__(16) unsigned short As[2][64 * 32];    //  8 KiB
    __shared__ __align__(16) unsigned short Bs[2][256 * 32];   // 32 KiB

    const int bid = blockIdx.x;
    const int g   = bid & 7;          // group ~ XCD (round-robin dispatch)
    const int rem = bid >> 3;
    const int nt  = rem & 1;
    const int mt  = rem >> 1;         // 0..127

    const int tid  = threadIdx.x;
    const int lane = tid & 63;
    const int w    = tid >> 6;        // 0..3 = wn
    const int lr   = lane & 15;
    const int lg   = lane >> 4;

    fv4 acc[4][4];
#pragma unroll
    for (int i = 0; i < 4; ++i)
#pragma unroll
        for (int j = 0; j < 4; ++j)
            acc[i][j] = (fv4){0.f, 0.f, 0.f, 0.f};

    const float* xg = x + (size_t)(mt * 64) * 4096 + g * 512;

    // ---- A staging: thread -> row arow (0..63), k-chunk ac (8 floats) ----
    const int arow = tid >> 2;
    const int ac   = tid & 3;
    const float* aSrc = xg + (size_t)arow * 4096 + ac * 8;
    const int aOff = arow * 64 + ((ac ^ ((arow >> 1) & 3)) * 16);  // bytes

    // ---- B staging: 4 gl_lds per wave, fully linear (packed layout) ----
    const unsigned short* bKt0 =
        bTgl + ((size_t)g * 16) * 2048 * 8 + (size_t)nt * 1024 * 8 +
        (size_t)(w * 256 + lane) * 8;

    // ---- fragment read slot (bytes); (row>>1)&3 == (lr>>1)&3 everywhere ----
    const int slotOff = (lg ^ ((lr >> 1) & 3)) * 16;
    const int aReadRow = lr * 64;               // + mi*16*64
    const int bReadRow = (w * 64 + lr) * 64;    // + ni*16*64

    float4 ar0_, ar1_;   // in-flight A (8 floats)

#define ISSUE_A(kt)                                                        \
    do {                                                                   \
        const float* s_ = aSrc + (kt) * 32;                                \
        ar0_ = *(const float4*)s_;                                         \
        ar1_ = *(const float4*)(s_ + 4);                                   \
    } while (0)

#define ISSUE_B(kt, bufw)                                                  \
    do { _Pragma("unroll") for (int p = 0; p < 4; ++p)                     \
        gl_lds16(bKt0 + (size_t)(kt) * 16384 + p * 512,                    \
                 (char*)&Bs[0][0] + (bufw) * 16384 + (w * 256 + p * 64) * 16); \
    } while (0)

#define WRITE_A(bufw)                                                      \
    do {                                                                   \
        uint4 w_;                                                          \
        w_.x = pk2(ar0_.x, ar0_.y); w_.y = pk2(ar0_.z, ar0_.w);            \
        w_.z = pk2(ar1_.x, ar1_.y); w_.w = pk2(ar1_.z, ar1_.w);            \
        *(uint4*)((char*)&As[0][0] + (bufw) * 4096 + aOff) = w_;           \
    } while (0)

#define COMPUTE(rb)                                                        \
    do {                                                                   \
        sv8 a_[4], b_[4];                                                  \
        _Pragma("unroll") for (int mi = 0; mi < 4; ++mi)                   \
            a_[mi] = *(const sv8*)((const char*)&As[0][0] + (rb) * 4096 +  \
                                   aReadRow + mi * 16 * 64 + slotOff);     \
        _Pragma("unroll") for (int ni = 0; ni < 4; ++ni)                   \
            b_[ni] = *(const sv8*)((const char*)&Bs[0][0] + (rb) * 16384 + \
                                   bReadRow + ni * 16 * 64 + slotOff);     \
        __builtin_amdgcn_s_setprio(1);                                     \
        _Pragma("unroll") for (int mi = 0; mi < 4; ++mi)                   \
        _Pragma("unroll") for (int ni = 0; ni < 4; ++ni)                   \
            acc[mi][ni] = __builtin_amdgcn_mfma_f32_16x16x32_bf16(         \
                b_[ni], a_[mi], acc[mi][ni], 0, 0, 0);                     \
        __builtin_amdgcn_s_setprio(0);                                     \
    } while (0)

    // ---- prologue: tile 0 staged into buf 0 ----
    ISSUE_A(0);
    ISSUE_B(0, 0);
    WRITE_A(0);          // compiler inserts vmcnt(4): A(0) only

    // steady state: at iter head, outstanding = 4 gl_lds of B(t)
#pragma unroll 1
    for (int t = 0; t < 15; ++t) {
        const int c = t & 1;
        ISSUE_A(t + 1);              // +2  (A regs for t+1)
        ISSUE_B(t + 1, c ^ 1);       // +4  (gl_lds into free buffer)
        VM(6);                       // B(t) landed; A(t+1)+B(t+1) in flight
        LGKM0();                     // our A(t) ds_write drained
        BAR();                       // buf c fully ready (all waves)
        COMPUTE(c);                  // ds_read frags + MFMA
        LGKM0();                     // our reads of buf c complete
        BAR();                       // buf c free: next iter may gl_lds it
        VM(4);                       // A(t+1) regs ready; B(t+1) still out
        WRITE_A(c ^ 1);
    }
    // tail t = 15
    VM(0);
    LGKM0();
    BAR();
    COMPUTE(1);

    // ---- epilogue: nontemporal float4 stores (lane holds 4 consecutive n)
    float* og = out + (size_t)(mt * 64) * 4096 + g * 512 + nt * 256 + w * 64;
#pragma unroll
    for (int mi = 0; mi < 4; ++mi)
#pragma unroll
        for (int ni = 0; ni < 4; ++ni)
            __builtin_nontemporal_store(
                acc[mi][ni],
                (fv4*)(og + (size_t)(mi * 16 + lr) * 4096 + ni * 16 + lg * 4));

#undef ISSUE_A
#undef ISSUE_B
#undef WRITE_A
#undef COMPUTE
}

// Safety net if ws is too small for the packed bf16 blocks (4 MiB).
__global__ void bl_fallback(const float* __restrict__ x,
                            const float* __restrict__ blocks,
                            float* __restrict__ out) {
    const int o = blockIdx.x * 256 + threadIdx.x;
    const int col = o & 4095;
    const int row = o >> 12;
    const int g = col >> 9;
    const int n = col & 511;
    const float* xr = x + (size_t)row * 4096 + g * 512;
    const float* wp = blocks + (size_t)g * 512 * 512 + n;
    float s = 0.f;
    for (int m = 0; m < 512; ++m) s += xr[m] * wp[(size_t)m * 512];
    out[o] = s;
}

extern "C" void kernel_launch(void* const* d_in, const int* in_sizes, int n_in,
                              void* d_out, int out_size, void* d_ws, size_t ws_size,
                              hipStream_t stream) {
    const float* x      = (const float*)d_in[0];
    const float* blocks = (const float*)d_in[1];
    float* out          = (float*)d_out;

    const size_t need = (size_t)8 * 16 * 2048 * 16;   // 4 MiB packed B
    if (ws_size >= need) {
        unsigned short* bTgl = (unsigned short*)d_ws;
        bl_pack<<<dim3(8, 8, 8), 256, 0, stream>>>(blocks, bTgl);
        bl_gemm<<<2048, 256, 0, stream>>>(x, bTgl, out);
    } else {
        bl_fallback<<<(8192 * 4096) / 256, 256, 0, stream>>>(x, blocks, out);
    }
}